// Round 6
// baseline (44.744 us; speedup 1.0000x reference)
//
#include <hip/hip_runtime.h>

#define GG   48
#define DD   256
#define HH   30
#define PP   1128          // GG*(GG-1)/2
#define VROW 264           // fp16 elems per padded LDS row (528 B, 16B-aligned)

#define OFF(i) (((i) * (95 - (i))) >> 1)   // pairs before row i (G=48)

typedef _Float16 half8 __attribute__((ext_vector_type(8)));
typedef _Float16 half4 __attribute__((ext_vector_type(4)));
typedef float    f32x4 __attribute__((ext_vector_type(4)));

__device__ __forceinline__ float sg(float x) { return 1.0f / (1.0f + __expf(-x)); }

__global__ __launch_bounds__(512, 4)
void afm_kernel(const int* __restrict__ group, const float* __restrict__ pe,
                const float* __restrict__ fe, const float* __restrict__ p,
                const float* __restrict__ W1, const float* __restrict__ b1,
                const float* __restrict__ W2, const float* __restrict__ b2,
                float* __restrict__ out)
{
    __shared__ __align__(16) _Float16 v[GG][VROW];      // 25344 B
    __shared__ __align__(16) union SU {
        _Float16 w1t[32][VROW];                          // 16896 B (rows: 30 W1 cols, p, 0)
        struct { float a_s[PP]; float s_s[PP]; } r;      // 9024 B, live after w1t dies
    } u;
    __shared__ int   gidx[GG];
    __shared__ float red[32];

    const int tid  = threadIdx.x;
    const int b    = blockIdx.x;
    const int lane = tid & 63;
    const int wv   = tid >> 6;       // wave 0..7
    const int colB = lane & 15;      // fragment row/col index
    const int kgrp = lane >> 4;      // k-group 0..3

    if (tid < GG) gidx[tid] = group[b * GG + tid];
    __syncthreads();

    float ff = (tid < GG) ? fe[gidx[tid]] : 0.0f;

    // per-lane MLP constants: this lane's C rows are h = kgrp*4+r (acc0) and
    // 16+kgrp*4+r (acc1). h=30 is the p-column, h=31 the zero column -> w2=0.
    float b1h[8], w2h[8];
#pragma unroll
    for (int r = 0; r < 4; ++r) {
        int h0 = kgrp * 4 + r;
        int h1 = 16 + kgrp * 4 + r;
        b1h[r]     = b1[h0];
        w2h[r]     = W2[h0];
        b1h[4 + r] = (h1 < HH) ? b1[h1] : 0.0f;
        w2h[4 + r] = (h1 < HH) ? W2[h1] : 0.0f;
    }
    const float b2v = b2[0];

    // stage v rows as fp16 (coalesced float4 gather, 8 rows per sweep)
    {
        int rr = tid >> 6, c = (tid & 63) * 4;
        for (int g0 = 0; g0 < GG; g0 += 8) {
            int g = g0 + rr;
            float4 f = *(const float4*)(pe + (size_t)gidx[g] * DD + c);
            half4 h4 = { (_Float16)f.x, (_Float16)f.y, (_Float16)f.z, (_Float16)f.w };
            *(half4*)&v[g][c] = h4;
        }
    }
    // stage W1^T (fp16), augmented: row 30 = p, row 31 = 0. Flat coalesced read.
    for (int k = tid; k < DD * HH; k += 512) {
        int d = k / HH, h = k - d * HH;
        u.w1t[h][d] = (_Float16)W1[k];
    }
    if (tid < DD) {
        u.w1t[30][tid] = (_Float16)p[tid];
        u.w1t[31][tid] = (_Float16)0.0f;
    }
    __syncthreads();

    // W fragments (A operand): lane holds rows h=colB and h=16+colB, k-chunk kgrp*8
    half8 wf0[8], wf1[8];
    {
        const _Float16* w0p = &u.w1t[colB][kgrp * 8];
        const _Float16* w1p = &u.w1t[16 + colB][kgrp * 8];
#pragma unroll
        for (int kt = 0; kt < 8; ++kt) {
            wf0[kt] = *(const half8*)(w0p + kt * 32);
            wf1[kt] = *(const half8*)(w1p + kt * 32);
        }
    }
    __syncthreads();   // all waves done reading w1t; a_s/s_s may now overwrite it

    // main loop: tiles (I-block of 16 i's) x (single j), j > I0, wave-strided by 8.
    // vi is re-read from LDS each kt (no register cache): keeps VGPR < 128 so
    // 2 blocks/CU * 8 waves = 4 waves/SIMD actually fit.
    for (int ib = 0; ib < 3; ++ib) {
        const int I0   = ib * 16;
        const int i_me = I0 + colB;          // this lane's pair-i (B-operand col)
        const _Float16* vip = &v[i_me][kgrp * 8];

        for (int j = I0 + 1 + wv; j < GG; j += 8) {
            const _Float16* vjp = &v[j][kgrp * 8];   // broadcast-class reads
            f32x4 acc0 = {0.f, 0.f, 0.f, 0.f};
            f32x4 acc1 = {0.f, 0.f, 0.f, 0.f};
#pragma unroll
            for (int kt = 0; kt < 8; ++kt) {
                half8 vi = *(const half8*)(vip + kt * 32);       // 2-way alias: free
                half8 e  = vi * (*(const half8*)(vjp + kt * 32)); // 4 v_pk_mul_f16
                acc0 = __builtin_amdgcn_mfma_f32_16x16x32_f16(wf0[kt], e, acc0, 0, 0, 0);
                acc1 = __builtin_amdgcn_mfma_f32_16x16x32_f16(wf1[kt], e, acc1, 0, 0, 0);
            }
            // C: row = h (kgrp*4+r / +16), col = pair q = colB. In-lane MLP partial:
            float t = 0.0f;
#pragma unroll
            for (int r = 0; r < 4; ++r) {
                t += sg(acc0[r] + b1h[r]) * w2h[r];
                t += sg(acc1[r] + b1h[4 + r]) * w2h[4 + r];   // masked terms add 0
            }
            t += __shfl_xor(t, 16);
            t += __shfl_xor(t, 32);
            if (i_me < j) {
                int pidx = OFF(i_me) + (j - i_me - 1);
                if (kgrp == 0) u.r.a_s[pidx] = sg(t + b2v);
                if (kgrp == 3) u.r.s_s[pidx] = acc1[2];   // h = 16+3*4+2 = 30 (e.p)
            }
        }
    }
    __syncthreads();

    // softmax over 1128 pairs + weighted sum + first-order (8-wave reduction)
    float lm = -1e30f;
    for (int q = tid; q < PP; q += 512) lm = fmaxf(lm, u.r.a_s[q]);
#pragma unroll
    for (int o = 32; o > 0; o >>= 1) lm = fmaxf(lm, __shfl_down(lm, o));
    if (lane == 0) red[wv] = lm;
    __syncthreads();
    float m = red[0];
#pragma unroll
    for (int k = 1; k < 8; ++k) m = fmaxf(m, red[k]);

    float ls = 0.0f, ln = 0.0f;
    for (int q = tid; q < PP; q += 512) {
        float ea = __expf(u.r.a_s[q] - m);
        ls += ea;
        ln += ea * u.r.s_s[q];
    }
    float lf = ff;
#pragma unroll
    for (int o = 32; o > 0; o >>= 1) {
        ls += __shfl_down(ls, o);
        ln += __shfl_down(ln, o);
        lf += __shfl_down(lf, o);
    }
    if (lane == 0) {
        red[8 + wv]  = ls;
        red[16 + wv] = ln;
        red[24 + wv] = lf;
    }
    __syncthreads();
    if (tid == 0) {
        float denom = 0.f, num = 0.f, first = 0.f;
#pragma unroll
        for (int k = 0; k < 8; ++k) {
            denom += red[8 + k];
            num   += red[16 + k];
            first += red[24 + k];
        }
        float second = num / denom;
        out[b] = sg(first + second) * 2.0f - 1.0f;
    }
}

extern "C" void kernel_launch(void* const* d_in, const int* in_sizes, int n_in,
                              void* d_out, int out_size, void* d_ws, size_t ws_size,
                              hipStream_t stream)
{
    const int*   group = (const int*)d_in[0];
    const float* pe    = (const float*)d_in[1];
    const float* fe    = (const float*)d_in[2];
    const float* p     = (const float*)d_in[3];
    const float* W1    = (const float*)d_in[4];
    const float* b1    = (const float*)d_in[5];
    const float* W2    = (const float*)d_in[6];
    const float* b2    = (const float*)d_in[7];
    float* out = (float*)d_out;

    afm_kernel<<<512, 512, 0, stream>>>(group, pe, fe, p, W1, b1, W2, b2, out);
}

// Round 7
// 36.371 us; speedup vs baseline: 1.2302x; 1.2302x over previous
//
#include <hip/hip_runtime.h>

#define GG   48
#define DD   256
#define HH   30
#define PP   1128          // GG*(GG-1)/2
#define VROW 264           // fp16 elems per padded LDS row (528 B, 16B-aligned)

#define OFF(i) (((i) * (95 - (i))) >> 1)   // pairs before row i (G=48)

typedef _Float16 half8 __attribute__((ext_vector_type(8)));
typedef _Float16 half4 __attribute__((ext_vector_type(4)));
typedef float    f32x4 __attribute__((ext_vector_type(4)));

// fast sigmoid: v_exp_f32 + v_rcp_f32 (~1 ULP each; threshold headroom ~400x)
__device__ __forceinline__ float sg(float x) {
    return __builtin_amdgcn_rcpf(1.0f + __expf(-x));
}

__global__ __launch_bounds__(512, 4)
void afm_kernel(const int* __restrict__ group, const float* __restrict__ pe,
                const float* __restrict__ fe, const float* __restrict__ p,
                const float* __restrict__ W1, const float* __restrict__ b1,
                const float* __restrict__ W2, const float* __restrict__ b2,
                float* __restrict__ out)
{
    __shared__ __align__(16) _Float16 v[GG][VROW];      // 25344 B
    __shared__ __align__(16) union SU {
        _Float16 w1t[32][VROW];                          // 16896 B (rows: 30 W1 cols, p, 0)
        struct { float a_s[PP]; float s_s[PP]; } r;      // 9024 B, live after w1t dies
    } u;
    __shared__ int   gidx[GG];
    __shared__ float red[32];

    const int tid  = threadIdx.x;
    const int b    = blockIdx.x;
    const int lane = tid & 63;
    const int wv   = tid >> 6;       // wave 0..7
    const int colB = lane & 15;      // fragment row/col index
    const int kgrp = lane >> 4;      // k-group 0..3

    if (tid < GG) gidx[tid] = group[b * GG + tid];
    __syncthreads();

    float ff = (tid < GG) ? fe[gidx[tid]] : 0.0f;

    // per-lane MLP constants (registers, loaded once from global — L3-resident).
    // This lane's C rows: h = kgrp*4+r (acc0) and 16+kgrp*4+r (acc1).
    // h=30 is the p-column (no bias, w2=0), h=31 the zero column.
    f32x4 bias0, bias1;
    float w2h[8];
#pragma unroll
    for (int r = 0; r < 4; ++r) {
        int h0 = kgrp * 4 + r;
        int h1 = 16 + kgrp * 4 + r;
        bias0[r]   = b1[h0];
        w2h[r]     = W2[h0];
        bias1[r]   = (h1 < HH) ? b1[h1] : 0.0f;
        w2h[4 + r] = (h1 < HH) ? W2[h1] : 0.0f;
    }
    const float b2v = b2[0];

    // stage v rows as fp16 (coalesced float4 gather, 8 rows per sweep)
    {
        int rr = tid >> 6, c = (tid & 63) * 4;
        for (int g0 = 0; g0 < GG; g0 += 8) {
            int g = g0 + rr;
            float4 f = *(const float4*)(pe + (size_t)gidx[g] * DD + c);
            half4 h4 = { (_Float16)f.x, (_Float16)f.y, (_Float16)f.z, (_Float16)f.w };
            *(half4*)&v[g][c] = h4;
        }
    }
    // stage W1^T (fp16), augmented: row 30 = p, row 31 = 0. Flat coalesced read.
    for (int k = tid; k < DD * HH; k += 512) {
        int d = k / HH, h = k - d * HH;
        u.w1t[h][d] = (_Float16)W1[k];
    }
    if (tid < DD) {
        u.w1t[30][tid] = (_Float16)p[tid];
        u.w1t[31][tid] = (_Float16)0.0f;
    }
    __syncthreads();

    // W fragments (A operand): lane holds rows h=colB and h=16+colB, k-chunk kgrp*8
    half8 wf0[8], wf1[8];
    {
        const _Float16* w0p = &u.w1t[colB][kgrp * 8];
        const _Float16* w1p = &u.w1t[16 + colB][kgrp * 8];
#pragma unroll
        for (int kt = 0; kt < 8; ++kt) {
            wf0[kt] = *(const half8*)(w0p + kt * 32);
            wf1[kt] = *(const half8*)(w1p + kt * 32);
        }
    }
    __syncthreads();   // all waves done reading w1t; a_s/s_s may now overwrite it

    // main loop: tiles (I-block of 16 i's) x (single j), j > I0, wave-strided by 8.
    // vi: kt 0..3 cached in regs (16 VGPR); kt 4..7 re-read from LDS (keeps
    // total VGPR <= 128 so 2 blocks/CU x 8 waves = 4 waves/SIMD fit).
    for (int ib = 0; ib < 3; ++ib) {
        const int I0   = ib * 16;
        const int i_me = I0 + colB;          // this lane's pair-i (B-operand col)
        const _Float16* vip = &v[i_me][kgrp * 8];
        half8 vif[4];
#pragma unroll
        for (int kt = 0; kt < 4; ++kt) vif[kt] = *(const half8*)(vip + kt * 32);

        for (int j = I0 + 1 + wv; j < GG; j += 8) {
            const _Float16* vjp = &v[j][kgrp * 8];   // broadcast-class reads
            f32x4 acc0 = bias0;                       // b1 folded into C-init
            f32x4 acc1 = bias1;
#pragma unroll
            for (int kt = 0; kt < 4; ++kt) {
                half8 e = vif[kt] * (*(const half8*)(vjp + kt * 32));
                acc0 = __builtin_amdgcn_mfma_f32_16x16x32_f16(wf0[kt], e, acc0, 0, 0, 0);
                acc1 = __builtin_amdgcn_mfma_f32_16x16x32_f16(wf1[kt], e, acc1, 0, 0, 0);
            }
#pragma unroll
            for (int kt = 4; kt < 8; ++kt) {
                half8 vi = *(const half8*)(vip + kt * 32);
                half8 e  = vi * (*(const half8*)(vjp + kt * 32));
                acc0 = __builtin_amdgcn_mfma_f32_16x16x32_f16(wf0[kt], e, acc0, 0, 0, 0);
                acc1 = __builtin_amdgcn_mfma_f32_16x16x32_f16(wf1[kt], e, acc1, 0, 0, 0);
            }
            // C: row = h (kgrp*4+r / +16), col = pair q = colB. In-lane MLP partial:
            float t = 0.0f;
#pragma unroll
            for (int r = 0; r < 4; ++r) {
                t += sg(acc0[r]) * w2h[r];
                t += sg(acc1[r]) * w2h[4 + r];   // masked terms add 0
            }
            t += __shfl_xor(t, 16);
            t += __shfl_xor(t, 32);
            if (i_me < j) {
                int pidx = OFF(i_me) + (j - i_me - 1);
                if (kgrp == 0) u.r.a_s[pidx] = sg(t + b2v);
                if (kgrp == 3) u.r.s_s[pidx] = acc1[2];   // h = 16+3*4+2 = 30 (e.p)
            }
        }
    }
    __syncthreads();

    // softmax over 1128 pairs + weighted sum + first-order (8-wave reduction)
    float lm = -1e30f;
    for (int q = tid; q < PP; q += 512) lm = fmaxf(lm, u.r.a_s[q]);
#pragma unroll
    for (int o = 32; o > 0; o >>= 1) lm = fmaxf(lm, __shfl_down(lm, o));
    if (lane == 0) red[wv] = lm;
    __syncthreads();
    float m = red[0];
#pragma unroll
    for (int k = 1; k < 8; ++k) m = fmaxf(m, red[k]);

    float ls = 0.0f, ln = 0.0f;
    for (int q = tid; q < PP; q += 512) {
        float ea = __expf(u.r.a_s[q] - m);
        ls += ea;
        ln += ea * u.r.s_s[q];
    }
    float lf = ff;
#pragma unroll
    for (int o = 32; o > 0; o >>= 1) {
        ls += __shfl_down(ls, o);
        ln += __shfl_down(ln, o);
        lf += __shfl_down(lf, o);
    }
    if (lane == 0) {
        red[8 + wv]  = ls;
        red[16 + wv] = ln;
        red[24 + wv] = lf;
    }
    __syncthreads();
    if (tid == 0) {
        float denom = 0.f, num = 0.f, first = 0.f;
#pragma unroll
        for (int k = 0; k < 8; ++k) {
            denom += red[8 + k];
            num   += red[16 + k];
            first += red[24 + k];
        }
        float second = num / denom;
        out[b] = sg(first + second) * 2.0f - 1.0f;
    }
}

extern "C" void kernel_launch(void* const* d_in, const int* in_sizes, int n_in,
                              void* d_out, int out_size, void* d_ws, size_t ws_size,
                              hipStream_t stream)
{
    const int*   group = (const int*)d_in[0];
    const float* pe    = (const float*)d_in[1];
    const float* fe    = (const float*)d_in[2];
    const float* p     = (const float*)d_in[3];
    const float* W1    = (const float*)d_in[4];
    const float* b1    = (const float*)d_in[5];
    const float* W2    = (const float*)d_in[6];
    const float* b2    = (const float*)d_in[7];
    float* out = (float*)d_out;

    afm_kernel<<<512, 512, 0, stream>>>(group, pe, fe, p, W1, b1, W2, b2, out);
}

// Round 8
// 35.175 us; speedup vs baseline: 1.2721x; 1.0340x over previous
//
#include <hip/hip_runtime.h>

#define GG   48
#define DD   256
#define HH   30
#define VROW 264           // fp16 elems per padded LDS row (528 B = 33*16, 16B-aligned)

typedef _Float16 half8 __attribute__((ext_vector_type(8)));
typedef _Float16 half4 __attribute__((ext_vector_type(4)));
typedef float    f32x4 __attribute__((ext_vector_type(4)));

// fast sigmoid: v_exp_f32 + v_rcp_f32 (~1 ULP; threshold headroom ~400x)
__device__ __forceinline__ float sg(float x) {
    return __builtin_amdgcn_rcpf(1.0f + __expf(-x));
}

// K1: one block = one (batch, half) pair. half0: i-block 0 (i in 0..15, j 1..47).
// half1: i-blocks 1,2 (i in 16..47). Partial {den, num, first} -> ws[b*2+half].
// No softmax-max pass needed: a = sigmoid(.) is in (0,1), exp(a) in (1, e).
__global__ __launch_bounds__(256, 3)
void afm_pairs_kernel(const int* __restrict__ group, const float* __restrict__ pe,
                      const float* __restrict__ fe, const float* __restrict__ p,
                      const float* __restrict__ W1, const float* __restrict__ b1,
                      const float* __restrict__ W2, const float* __restrict__ b2,
                      float4* __restrict__ ws)
{
    // w1t staged first, read into registers, then region reused for v.
    __shared__ __align__(16) union SU {
        _Float16 w1t[32][VROW];              // 16896 B (rows: 30 W1 cols, p, zeros)
        _Float16 v[GG][VROW];                // 25344 B
    } u;
    __shared__ int   gidx[GG];
    __shared__ float red[4][3];

    const int tid  = threadIdx.x;
    const int b    = blockIdx.x >> 1;
    const int half = blockIdx.x & 1;
    const int lane = tid & 63;
    const int wv   = tid >> 6;       // wave 0..3
    const int colB = lane & 15;      // fragment row/col index
    const int kgrp = lane >> 4;      // k-group 0..3

    if (tid < GG) gidx[tid] = group[b * GG + tid];

    // stage W1^T (fp16), augmented: row 30 = p, row 31 = 0. Flat coalesced read.
    for (int k = tid; k < DD * HH; k += 256) {
        int d = k / HH, h = k - d * HH;
        u.w1t[h][d] = (_Float16)W1[k];
    }
    if (tid < DD) {
        u.w1t[30][tid] = (_Float16)p[tid];
        u.w1t[31][tid] = (_Float16)0.0f;
    }

    // per-lane MLP constants. This lane's C rows: h = kgrp*4+r (acc0), 16+kgrp*4+r (acc1).
    f32x4 bias0, bias1;
    float w2h[8];
#pragma unroll
    for (int r = 0; r < 4; ++r) {
        int h0 = kgrp * 4 + r;
        int h1 = 16 + kgrp * 4 + r;
        bias0[r]   = b1[h0];
        w2h[r]     = W2[h0];
        bias1[r]   = (h1 < HH) ? b1[h1] : 0.0f;
        w2h[4 + r] = (h1 < HH) ? W2[h1] : 0.0f;
    }
    const float b2v = b2[0];
    __syncthreads();

    // first-order partial: half0 -> group slots 0..23, half1 -> 24..47
    float ff = (tid < 24) ? fe[gidx[24 * half + tid]] : 0.0f;

    // W fragments: lane holds rows h=colB and h=16+colB, k-chunk kgrp*8
    half8 wf0[8], wf1[8];
    {
        const _Float16* w0p = &u.w1t[colB][kgrp * 8];
        const _Float16* w1p = &u.w1t[16 + colB][kgrp * 8];
#pragma unroll
        for (int kt = 0; kt < 8; ++kt) {
            wf0[kt] = *(const half8*)(w0p + kt * 32);
            wf1[kt] = *(const half8*)(w1p + kt * 32);
        }
    }
    __syncthreads();   // wf reads done; v may overwrite the region

    // stage the v rows this half needs (half0: 0..47, half1: 16..47)
    {
        const int row0 = half ? 16 : 0;
        const int nr   = GG - row0;
        int rr = tid >> 6, c = (tid & 63) * 4;
        for (int g0 = 0; g0 < nr; g0 += 4) {
            int g = row0 + g0 + rr;
            float4 f = *(const float4*)(pe + (size_t)gidx[g] * DD + c);
            half4 h4 = { (_Float16)f.x, (_Float16)f.y, (_Float16)f.z, (_Float16)f.w };
            *(half4*)&u.v[g][c] = h4;
        }
    }
    __syncthreads();

    float den = 0.0f, num = 0.0f;

    const int ib_lo = half ? 1 : 0;
    const int ib_hi = half ? 3 : 1;
    for (int ib = ib_lo; ib < ib_hi; ++ib) {
        const int I0   = ib * 16;
        const int i_me = I0 + colB;          // this lane's pair-i (B-operand col)
        half8 vif[8];
        {
            const _Float16* vr = &u.v[i_me][kgrp * 8];
#pragma unroll
            for (int kt = 0; kt < 8; ++kt) vif[kt] = *(const half8*)(vr + kt * 32);
        }

        for (int j = I0 + 1 + wv; j < GG; j += 4) {
            const _Float16* vjp = &u.v[j][kgrp * 8];   // broadcast-class reads
            f32x4 acc0 = bias0;                         // b1 folded into C-init
            f32x4 acc1 = bias1;
#pragma unroll
            for (int kt = 0; kt < 8; ++kt) {
                half8 e = vif[kt] * (*(const half8*)(vjp + kt * 32));  // 4 v_pk_mul_f16
                acc0 = __builtin_amdgcn_mfma_f32_16x16x32_f16(wf0[kt], e, acc0, 0, 0, 0);
                acc1 = __builtin_amdgcn_mfma_f32_16x16x32_f16(wf1[kt], e, acc1, 0, 0, 0);
            }
            // C: row = h, col = pair (colB). In-lane MLP partial over this lane's 8 h's:
            float t = 0.0f;
#pragma unroll
            for (int r = 0; r < 4; ++r) {
                t += sg(acc0[r]) * w2h[r];
                t += sg(acc1[r]) * w2h[4 + r];   // masked terms add 0
            }
            t += __shfl_xor(t, 16);
            t += __shfl_xor(t, 32);              // now all lanes hold full t
            float ea = __expf(sg(t + b2v));      // exp(a), a in (0,1): no max needed
            // kgrp==3 lanes own s = z[h=30] = acc1[2]; they accumulate den/num
            if (kgrp == 3 && i_me < j) {
                den += ea;
                num += ea * acc1[2];
            }
        }
    }

    // block reduction of den, num, ff
#pragma unroll
    for (int o = 32; o > 0; o >>= 1) {
        den += __shfl_down(den, o);
        num += __shfl_down(num, o);
        ff  += __shfl_down(ff, o);
    }
    if (lane == 0) { red[wv][0] = den; red[wv][1] = num; red[wv][2] = ff; }
    __syncthreads();
    if (tid == 0) {
        float d = 0.f, n = 0.f, f = 0.f;
#pragma unroll
        for (int k = 0; k < 4; ++k) { d += red[k][0]; n += red[k][1]; f += red[k][2]; }
        ws[blockIdx.x] = make_float4(d, n, f, 0.0f);
    }
}

// K2: combine the two halves of each batch
__global__ __launch_bounds__(256)
void afm_combine_kernel(const float4* __restrict__ ws, float* __restrict__ out, int B)
{
    int i = blockIdx.x * 256 + threadIdx.x;
    if (i < B) {
        float4 A = ws[2 * i];
        float4 Bv = ws[2 * i + 1];
        float first  = A.z + Bv.z;
        float second = (A.y + Bv.y) / (A.x + Bv.x);
        out[i] = sg(first + second) * 2.0f - 1.0f;
    }
}

extern "C" void kernel_launch(void* const* d_in, const int* in_sizes, int n_in,
                              void* d_out, int out_size, void* d_ws, size_t ws_size,
                              hipStream_t stream)
{
    const int*   group = (const int*)d_in[0];
    const float* pe    = (const float*)d_in[1];
    const float* fe    = (const float*)d_in[2];
    const float* p     = (const float*)d_in[3];
    const float* W1    = (const float*)d_in[4];
    const float* b1    = (const float*)d_in[5];
    const float* W2    = (const float*)d_in[6];
    const float* b2    = (const float*)d_in[7];
    float*  out = (float*)d_out;
    float4* ws  = (float4*)d_ws;
    const int B = out_size;   // 512

    afm_pairs_kernel<<<2 * B, 256, 0, stream>>>(group, pe, fe, p, W1, b1, W2, b2, ws);
    afm_combine_kernel<<<(B + 255) / 256, 256, 0, stream>>>(ws, out, B);
}